// Round 10
// baseline (288.825 us; speedup 1.0000x reference)
//
#include <hip/hip_runtime.h>
#include <hip/hip_bf16.h>
#include <hip/hip_fp16.h>

#define N_USER 150000
#define M_ITEM 30000
#define N_NODES 180000
#define E2 1200000
#define BATCH 1024
#define AUX_W 10246
#define KP_G 32
#define KP_D 2208
#define KP_A 8064
#define NBKT 265       // 147 user buckets (1024 rows) + 118 item buckets (256 rows)
#define WT_BLKS 2576   // ((KP_G+KP_D+KP_A)*64 + 255)/256
#define BCNT_BLKS 293  // (E2 + 4095)/4096
#define MH_BLKS 672    // 16 genre + 144 director (9 x16) + 512 actor (32 x16), K-chunk 256
#define CVT_BLKS 5625  // N_NODES*8/256 (exactly)

typedef __attribute__((ext_vector_type(8))) short short8;
typedef __attribute__((ext_vector_type(8))) unsigned short ushort8_t;
typedef __attribute__((ext_vector_type(4))) float f32x4;

__device__ __forceinline__ int bucket_of(int r) {
    return r < N_USER ? (r >> 10) : 147 + ((r - N_USER) >> 8);
}

// inline dtype detect (wave-uniform): bf16 data reads small; f32-as-bf16 huge.
__device__ __forceinline__ int detect_f32(const void* probe) {
    float v = __bfloat162float(((const __hip_bfloat16*)probe)[threadIdx.x & 63]);
    unsigned long long m = __ballot(!(fabsf(v) < 1000.0f));
    return __popcll(m) > 8;
}

// ---------------- fused prep: bucket counts + table cvt + Wt pack ----------
// R6: count blocks FIRST (long pole overlaps light cvt/WT blocks).
struct CvtSeg { const void* src; float* dst; int n; int blk0; };
struct CvtBatch { CvtSeg seg[16]; };

__global__ void __launch_bounds__(256) k_prep(CvtBatch cb, int cvtBlks,
                                              const void* Wg, const void* Wd, const void* Wa,
                                              unsigned short* WtG, unsigned short* WtD, unsigned short* WtA,
                                              const int* __restrict__ grow, int* __restrict__ bucket_tot,
                                              const void* probe) {
    int blk = blockIdx.x, tid = threadIdx.x;
    if (blk < BCNT_BLKS) {                     // --- bucket counts (first: long pole)
        __shared__ int h[NBKT];
        for (int i = tid; i < NBKT; i += 256) h[i] = 0;
        __syncthreads();
        int idx0 = blk * 4096;
        #pragma unroll
        for (int k = 0; k < 16; ++k) {
            int i = idx0 + k * 256 + tid;
            if (i < E2) atomicAdd(&h[bucket_of(grow[i])], 1);
        }
        __syncthreads();
        for (int i = tid; i < NBKT; i += 256) if (h[i]) atomicAdd(&bucket_tot[i], h[i]);
        return;
    }
    if (blk < BCNT_BLKS + cvtBlks) {           // --- small-table f32 conversion
        int isf32 = detect_f32(probe);
        int cblk = blk - BCNT_BLKS;
        int si = 0;
        #pragma unroll
        for (int i = 0; i < 16; ++i) if (cblk >= cb.seg[i].blk0) si = i;
        const CvtSeg sg = cb.seg[si];
        int i = (cblk - sg.blk0) * 256 + tid;
        if (i >= sg.n) return;
        if (isf32) sg.dst[i] = ((const float*)sg.src)[i];
        else       sg.dst[i] = __bfloat162float(((const __hip_bfloat16*)sg.src)[i]);
        return;
    }
    {                                          // --- Wt B-fragment pack
        int isf32 = detect_f32(probe);
        int t = (blk - BCNT_BLKS - cvtBlks) * 256 + tid;
        if (t >= (KP_G + KP_D + KP_A) * 64) return;
        int kp = t >> 6, n = t & 63;
        int k, K; const void* src; unsigned short* dst;
        if (kp < KP_G)              { k = kp;               K = 25;   src = Wg; dst = WtG; }
        else if (kp < KP_G + KP_D)  { k = kp - KP_G;        K = 2186; src = Wd; dst = WtD; }
        else                        { k = kp - KP_G - KP_D; K = 8030; src = Wa; dst = WtA; }
        unsigned short v = 0;
        if (k < K) {
            if (isf32) {
                __hip_bfloat16 h = __float2bfloat16(((const float*)src)[(size_t)k * 64 + n]);
                v = *(unsigned short*)&h;
            } else {
                v = ((const unsigned short*)src)[(size_t)k * 64 + n];
            }
        }
        dst[(((size_t)(k >> 5) * 64 + n) * 4 + ((k >> 3) & 3)) * 8 + (k & 7)] = v;
    }
}

// ---------------- bucket scan ----------------
__global__ void __launch_bounds__(512) k_bscan(const int* __restrict__ bucket_tot,
                                               int* __restrict__ bucket_base,
                                               int* __restrict__ bucketcur) {
    __shared__ int s[512];
    int tid = threadIdx.x;
    s[tid] = (tid < NBKT) ? bucket_tot[tid] : 0;
    __syncthreads();
    for (int off = 1; off < 512; off <<= 1) {
        int v = (tid >= off) ? s[tid - off] : 0;
        __syncthreads();
        s[tid] += v;
        __syncthreads();
    }
    int excl = tid ? s[tid - 1] : 0;
    bucket_base[tid] = excl;                 // bucket_base[NBKT] = E2
    if (tid < NBKT) bucketcur[tid] = excl;
}

// ---------------- mhgemm device body (R3: prefetched, mad-built af) --------
__device__ void mhgemm_body(int blk, const int* __restrict__ aux,
                            const unsigned short* __restrict__ WtG,
                            const unsigned short* __restrict__ WtD,
                            const unsigned short* __restrict__ WtA,
                            float* __restrict__ Xmh, float* __restrict__ cntf) {
    int seg, rb, k0, klen, Kseg, auxoff;
    const unsigned short* Wt;
    if (blk < 16)       { seg = 0; rb = blk;                      k0 = 0;              klen = 25;                  Kseg = 25;   auxoff = 1;    Wt = WtG; }
    else if (blk < 160) { int t = blk - 16;  seg = 1; rb = t & 15; k0 = (t >> 4) * 256; klen = min(256, 2186 - k0); Kseg = 2186; auxoff = 26;   Wt = WtD; }
    else                { int t = blk - 160; seg = 2; rb = t & 15; k0 = (t >> 4) * 256; klen = min(256, 8030 - k0); Kseg = 8030; auxoff = 2212; Wt = WtA; }
    int lane = threadIdx.x & 63, wave = threadIdx.x >> 6;
    int m = lane & 15, quad = lane >> 4;
    int row = rb * 64 + wave * 16 + m;
    const int* arow = aux + (size_t)row * AUX_W + auxoff;

    f32x4 acc0 = {0.f,0.f,0.f,0.f}, acc1 = acc0, acc2 = acc0, acc3 = acc0;
    int isum = 0;
    int nchunk = (klen + 31) >> 5;
    int pa[8], na[8];
    auto lda = [&](int kci, int (&A)[8]) {
        int kb = k0 + kci * 32 + quad * 8;
        if (kb + 8 <= Kseg) {
            #pragma unroll
            for (int j = 0; j < 8; ++j) A[j] = arow[kb + j];
        } else {
            #pragma unroll
            for (int j = 0; j < 8; ++j) A[j] = (kb + j < Kseg) ? arow[kb + j] : 0;
        }
    };
    lda(0, pa);
    for (int kci = 0; kci < nchunk; ++kci) {
        if (kci + 1 < nchunk) lda(kci + 1, na);   // prefetch next chunk's aux
        union { unsigned u[4]; short8 s; } af;
        af.u[0] = (unsigned)pa[0] * 16256u + (unsigned)pa[1] * 0x3F800000u;
        af.u[1] = (unsigned)pa[2] * 16256u + (unsigned)pa[3] * 0x3F800000u;
        af.u[2] = (unsigned)pa[4] * 16256u + (unsigned)pa[5] * 0x3F800000u;
        af.u[3] = (unsigned)pa[6] * 16256u + (unsigned)pa[7] * 0x3F800000u;
        isum += pa[0] + pa[1] + pa[2] + pa[3] + pa[4] + pa[5] + pa[6] + pa[7];
        size_t kcg = (size_t)(k0 >> 5) + kci;
        const unsigned short* bp = Wt + ((kcg * 64 + m) * 4 + quad) * 8;
        short8 b0 = *(const short8*)(bp);
        short8 b1 = *(const short8*)(bp + 512);
        short8 b2 = *(const short8*)(bp + 1024);
        short8 b3 = *(const short8*)(bp + 1536);
        acc0 = __builtin_amdgcn_mfma_f32_16x16x32_bf16(af.s, b0, acc0, 0, 0, 0);
        acc1 = __builtin_amdgcn_mfma_f32_16x16x32_bf16(af.s, b1, acc1, 0, 0, 0);
        acc2 = __builtin_amdgcn_mfma_f32_16x16x32_bf16(af.s, b2, acc2, 0, 0, 0);
        acc3 = __builtin_amdgcn_mfma_f32_16x16x32_bf16(af.s, b3, acc3, 0, 0, 0);
        #pragma unroll
        for (int j = 0; j < 8; ++j) pa[j] = na[j];
    }
    float asum = (float)isum;
    asum += __shfl_xor(asum, 16);
    asum += __shfl_xor(asum, 32);
    if (quad == 0) atomicAdd(&cntf[seg * BATCH + row], asum);
    float* xbase = Xmh + ((size_t)seg * BATCH + rb * 64 + wave * 16 + quad * 4) * 64;
    #pragma unroll
    for (int reg = 0; reg < 4; ++reg) {
        float* xr = xbase + (size_t)reg * 64;
        atomicAdd(&xr[ 0 + m], acc0[reg]);
        atomicAdd(&xr[16 + m], acc1[reg]);
        atomicAdd(&xr[32 + m], acc2[reg]);
        atomicAdd(&xr[48 + m], acc3[reg]);
    }
}

// ---------------- P1: mhgemm + binning + unscaled cvt + tacc0 --------------
// R9: binned compacted to int (bucket implicit in position):
//   user bucket: (c<<10)|(r&1023); item bucket: (c<<8)|((r-N_USER)&255).
// tacc0 moved here from spmv_w (reads only raw+ids, no CSR dependency).
// Blocks: [0,672) mhgemm; [672,965) binning; [965,6590) cvt; [6590,7102) tacc0.
__global__ void __launch_bounds__(256) k_p1(const int* __restrict__ grow, const int* __restrict__ gcol,
                                            int* __restrict__ bucketcur, int* __restrict__ binned,
                                            const int* __restrict__ aux,
                                            const unsigned short* __restrict__ WtG,
                                            const unsigned short* __restrict__ WtD,
                                            const unsigned short* __restrict__ WtA,
                                            float* __restrict__ Xmh, float* __restrict__ cntf,
                                            const void* rawU, const void* rawI,
                                            __half* __restrict__ embH,
                                            float* __restrict__ tacc,
                                            const int* __restrict__ uids, const int* __restrict__ iids) {
    int blk = blockIdx.x;
    if (blk < MH_BLKS) {
        mhgemm_body(blk, aux, WtG, WtD, WtA, Xmh, cntf);
        return;
    }
    if (blk < MH_BLKS + BCNT_BLKS) {          // --- edge binning (compact enc)
        __shared__ int h1[NBKT], base1[NBKT];
        int tid = threadIdx.x;
        for (int i = tid; i < NBKT; i += 256) h1[i] = 0;
        __syncthreads();
        int idx0 = (blk - MH_BLKS) * 4096;
        int r[16], c[16];
        #pragma unroll
        for (int k = 0; k < 16; ++k) {
            int i = idx0 + k * 256 + tid;
            if (i < E2) {
                r[k] = grow[i]; c[k] = gcol[i];
                atomicAdd(&h1[bucket_of(r[k])], 1);
            } else r[k] = -1;
        }
        __syncthreads();
        for (int i = tid; i < NBKT; i += 256) {
            base1[i] = h1[i] ? atomicAdd(&bucketcur[i], h1[i]) : 0;
            h1[i] = 0;
        }
        __syncthreads();
        #pragma unroll
        for (int k = 0; k < 16; ++k) {
            if (r[k] >= 0) {
                int b = bucket_of(r[k]);
                int p = base1[b] + atomicAdd(&h1[b], 1);
                int enc = (r[k] < N_USER) ? ((c[k] << 10) | (r[k] & 1023))
                                          : ((c[k] << 8) | ((r[k] - N_USER) & 255));
                binned[p] = enc;
            }
        }
        return;
    }
    if (blk < MH_BLKS + BCNT_BLKS + CVT_BLKS) {   // --- unscaled emb cvt (16B/lane)
        int isf32 = detect_f32(rawU);
        int q = (blk - MH_BLKS - BCNT_BLKS) * 256 + threadIdx.x;  // octet (8 elems)
        int r = q >> 3;                            // CVT_BLKS*256 == N_NODES*8 exactly
        const void* src; size_t qq;
        if (r < N_USER) { src = rawU; qq = (size_t)q; }
        else            { src = rawI; qq = (size_t)q - (size_t)N_USER * 8; }
        float f[8];
        if (isf32) {
            float4 a = ((const float4*)src)[qq * 2], b = ((const float4*)src)[qq * 2 + 1];
            f[0]=a.x; f[1]=a.y; f[2]=a.z; f[3]=a.w; f[4]=b.x; f[5]=b.y; f[6]=b.z; f[7]=b.w;
        } else {
            ushort8_t u = ((const ushort8_t*)src)[qq];
            #pragma unroll
            for (int i = 0; i < 8; ++i) {
                unsigned short us = u[i];
                f[i] = __bfloat162float(*(__hip_bfloat16*)&us);
            }
        }
        ushort8_t o;
        #pragma unroll
        for (int i = 0; i < 8; ++i) {
            __half h = __float2half(f[i]);
            o[i] = *(unsigned short*)&h;
        }
        ((ushort8_t*)embH)[(size_t)q] = o;
        return;
    }
    {                                         // --- tacc0 init from RAW rows
        int isf32 = detect_f32(rawU);
        int lane = threadIdx.x & 63;
        int t = (blk - MH_BLKS - BCNT_BLKS - CVT_BLKS) * 4 + (threadIdx.x >> 6);
        const void* s; size_t ri;
        if (t < BATCH) { s = rawU; ri = (size_t)uids[t]; }
        else           { s = rawI; ri = (size_t)iids[t - BATCH]; }
        float v;
        if (isf32) v = ((const float*)s)[ri * 64 + lane];
        else       v = __bfloat162float(((const __hip_bfloat16*)s)[ri * 64 + lane]);
        tacc[(size_t)t * 64 + lane] = v;
    }
}

// ---------------- P2: per-bucket sort + packed (start,end) + factors -------
// R9: decodes compact binned entries (bucket-type known from block index).
__global__ void __launch_bounds__(256) k_p2(const int* __restrict__ binned, const int* __restrict__ bb,
                                            int* __restrict__ cols, int2* __restrict__ moffs,
                                            float* __restrict__ dinv, float* __restrict__ dsq,
                                            float* __restrict__ gsc) {
    __shared__ int h[1024];
    __shared__ int ws2[256];
    int b = blockIdx.x, tid = threadIdx.x;
    int r0, r1, shift, mask;
    if (b < 147) { r0 = b << 10; r1 = min((b + 1) << 10, N_USER); shift = 10; mask = 1023; }
    else         { r0 = N_USER + ((b - 147) << 8); r1 = min(N_USER + ((b - 146) << 8), N_NODES); shift = 8; mask = 255; }
    int s0 = bb[b], e0 = bb[b + 1];
    for (int i = tid; i < 1024; i += 256) h[i] = 0;
    __syncthreads();
    for (int j = s0 + tid; j < e0; j += 256) atomicAdd(&h[binned[j] & mask], 1);
    __syncthreads();
    int t0 = tid * 4;
    int a0 = h[t0], a1 = h[t0 + 1], a2 = h[t0 + 2], a3 = h[t0 + 3];
    ws2[tid] = a0 + a1 + a2 + a3;
    __syncthreads();
    for (int off = 1; off < 256; off <<= 1) {
        int v = (tid >= off) ? ws2[tid - off] : 0;
        __syncthreads();
        ws2[tid] += v;
        __syncthreads();
    }
    int excl = tid ? ws2[tid - 1] : 0;
    int ex[4] = { excl, excl + a0, excl + a0 + a1, excl + a0 + a1 + a2 };
    int ac[4] = { a0, a1, a2, a3 };
    #pragma unroll
    for (int i = 0; i < 4; ++i) {
        int row = r0 + t0 + i;
        if (row < r1) {
            moffs[row] = make_int2(s0 + ex[i], s0 + ex[i] + ac[i]);
            float deg = (float)ac[i];
            bool nz = deg > 0.f;
            dinv[row] = nz ? rsqrtf(deg) : 0.f;
            dsq[row]  = nz ? 1.f / deg  : 0.f;
            gsc[row]  = nz ? sqrtf(deg) : 0.f;
        }
        h[t0 + i] = ex[i];
    }
    __syncthreads();
    for (int j = s0 + tid; j < e0; j += 256) {
        int v = binned[j];
        int p = s0 + atomicAdd(&h[v & mask], 1);
        cols[p] = ((unsigned)v >> shift) << 7;   // byte offset into a 64-half row
    }
}

// ---------------- L1 SpMV: gather embH (f16) with per-edge dinv weight -----
// dst[r] = dsq[r] * sum_c dinv[c]*embH[c]. 8 rows/wave, 16B slice/lane.
// R9: 8-edge main loop (deeper MLP for item rows, deg~20); (256,4) bounds for
// the extra VGPRs. Cargo: [spmvN,+512) mark moffs2 (tacc0 moved to p1).
__global__ void __launch_bounds__(256, 4) k_spmv_w(const __half* __restrict__ src,
                                                   __half* __restrict__ dst,
                                                   const int2* __restrict__ moffs_in,
                                                   const int* __restrict__ cols,
                                                   const float* __restrict__ dinv,
                                                   const float* __restrict__ dsq,
                                                   int spmvN,
                                                   const int* __restrict__ uids, const int* __restrict__ iids,
                                                   int2* __restrict__ moffs2) {
    int tid = threadIdx.x, lane = tid & 63;
    int blk = blockIdx.x;
    if (blk >= spmvN) {                       // mark moffs2[r] for T u N(T)
        int t = (blk - spmvN) * 4 + (tid >> 6);
        int r = (t < BATCH) ? uids[t] : (N_USER + iids[t - BATCH]);
        int2 se = moffs_in[r];
        if (lane == 0) moffs2[r] = se;
        for (int j = se.x + lane; j < se.y; j += 64) {
            int c = (unsigned)cols[j] >> 7;
            moffs2[c] = moffs_in[c];          // benign dup races: same value
        }
        return;
    }
    int wid8 = blk * 4 + (tid >> 6);          // wave id; 8 rows per wave
    int g = lane >> 3, l8 = lane & 7;
    int r = wid8 * 8 + g;                     // r < N_NODES exactly
    int2 se = moffs_in[r];
    int s = se.x, e = se.y;
    const char* sb = (const char*)src + (l8 << 4);   // 16B slice of gathered row
    float a[8] = {0.f,0.f,0.f,0.f,0.f,0.f,0.f,0.f};
    int j0 = s;
    for (; j0 + 8 <= e; j0 += 8) {            // 8 edges/iter (item rows)
        int c[8]; float w[8];
        #pragma unroll
        for (int u = 0; u < 8; ++u) { c[u] = cols[j0 + u]; w[u] = dinv[(unsigned)c[u] >> 7]; }
        float4 rv[8];
        #pragma unroll
        for (int u = 0; u < 8; ++u) rv[u] = *(const float4*)(sb + (size_t)(unsigned)c[u]);
        #pragma unroll
        for (int u = 0; u < 8; ++u) {
            const __half2* h = (const __half2*)&rv[u];
            float2 f0 = __half22float2(h[0]), f1 = __half22float2(h[1]);
            float2 f2 = __half22float2(h[2]), f3 = __half22float2(h[3]);
            a[0] = fmaf(w[u], f0.x, a[0]); a[1] = fmaf(w[u], f0.y, a[1]);
            a[2] = fmaf(w[u], f1.x, a[2]); a[3] = fmaf(w[u], f1.y, a[3]);
            a[4] = fmaf(w[u], f2.x, a[4]); a[5] = fmaf(w[u], f2.y, a[5]);
            a[6] = fmaf(w[u], f3.x, a[6]); a[7] = fmaf(w[u], f3.y, a[7]);
        }
    }
    if (j0 + 4 <= e) {                        // exact 4 edges
        int c[4]; float w[4];
        #pragma unroll
        for (int u = 0; u < 4; ++u) { c[u] = cols[j0 + u]; w[u] = dinv[(unsigned)c[u] >> 7]; }
        float4 rv[4];
        #pragma unroll
        for (int u = 0; u < 4; ++u) rv[u] = *(const float4*)(sb + (size_t)(unsigned)c[u]);
        #pragma unroll
        for (int u = 0; u < 4; ++u) {
            const __half2* h = (const __half2*)&rv[u];
            float2 f0 = __half22float2(h[0]), f1 = __half22float2(h[1]);
            float2 f2 = __half22float2(h[2]), f3 = __half22float2(h[3]);
            a[0] = fmaf(w[u], f0.x, a[0]); a[1] = fmaf(w[u], f0.y, a[1]);
            a[2] = fmaf(w[u], f1.x, a[2]); a[3] = fmaf(w[u], f1.y, a[3]);
            a[4] = fmaf(w[u], f2.x, a[4]); a[5] = fmaf(w[u], f2.y, a[5]);
            a[6] = fmaf(w[u], f3.x, a[6]); a[7] = fmaf(w[u], f3.y, a[7]);
        }
        j0 += 4;
    }
    if (j0 < e) {                             // 1-3 remaining, clamped+weighted
        int c[4]; float w[4];
        #pragma unroll
        for (int u = 0; u < 4; ++u) {
            int j = j0 + u;
            c[u] = cols[min(j, e - 1)];
            w[u] = (j < e) ? dinv[(unsigned)c[u] >> 7] : 0.f;
        }
        float4 rv[4];
        #pragma unroll
        for (int u = 0; u < 4; ++u) rv[u] = *(const float4*)(sb + (size_t)(unsigned)c[u]);
        #pragma unroll
        for (int u = 0; u < 4; ++u) {
            const __half2* h = (const __half2*)&rv[u];
            float2 f0 = __half22float2(h[0]), f1 = __half22float2(h[1]);
            float2 f2 = __half22float2(h[2]), f3 = __half22float2(h[3]);
            a[0] = fmaf(w[u], f0.x, a[0]); a[1] = fmaf(w[u], f0.y, a[1]);
            a[2] = fmaf(w[u], f1.x, a[2]); a[3] = fmaf(w[u], f1.y, a[3]);
            a[4] = fmaf(w[u], f2.x, a[4]); a[5] = fmaf(w[u], f2.y, a[5]);
            a[6] = fmaf(w[u], f3.x, a[6]); a[7] = fmaf(w[u], f3.y, a[7]);
        }
    }
    if (e > s) {
        float d = dsq[r];
        float4 ov;
        __half2* op = (__half2*)&ov;
        op[0] = __floats2half2_rn(a[0] * d, a[1] * d);
        op[1] = __floats2half2_rn(a[2] * d, a[3] * d);
        op[2] = __floats2half2_rn(a[4] * d, a[5] * d);
        op[3] = __floats2half2_rn(a[6] * d, a[7] * d);
        *(float4*)((char*)dst + ((size_t)r << 7) + (l8 << 4)) = ov;
    }
}

// ---------------- L2 SpMV (half domain) + tacc-f1 cargo --------------------
// R9: 8-edge main loop added (same per-lane fma order -> bit-identical).
__global__ void __launch_bounds__(256, 4) k_spmv(const __half* __restrict__ src, __half* __restrict__ dst,
                                                 const int2* __restrict__ moffs_in, const int* __restrict__ cols,
                                                 const float* __restrict__ dsq,
                                                 int spmvN, float* __restrict__ tacc,
                                                 const int* __restrict__ uids, const int* __restrict__ iids,
                                                 const float* __restrict__ gsc) {
    int tid = threadIdx.x, lane = tid & 63;
    int blk = blockIdx.x;
    if (blk >= spmvN) {                       // tacc += gsc[r]*src[r] (deg>0 guard)
        int t = (blk - spmvN) * 4 + (tid >> 6);
        int r = (t < BATCH) ? uids[t] : (N_USER + iids[t - BATCH]);
        float g = gsc[r];
        float h = __half2float(src[(size_t)r * 64 + lane]);
        tacc[(size_t)t * 64 + lane] += (g > 0.f) ? h * g : 0.f;
        return;
    }
    int wid8 = blk * 4 + (tid >> 6);          // wave id; 8 rows per wave
    int g = lane >> 3, l8 = lane & 7;
    int r = wid8 * 8 + g;
    int2 se = moffs_in[r];
    int s = se.x, e = se.y;
    const char* sb = (const char*)src + (l8 << 4);   // 16B slice of gathered row
    float a[8] = {0.f,0.f,0.f,0.f,0.f,0.f,0.f,0.f};
    int j0 = s;
    for (; j0 + 8 <= e; j0 += 8) {            // 8 edges/iter (item rows)
        int c[8];
        #pragma unroll
        for (int u = 0; u < 8; ++u) c[u] = cols[j0 + u];
        float4 rv[8];
        #pragma unroll
        for (int u = 0; u < 8; ++u) rv[u] = *(const float4*)(sb + (size_t)(unsigned)c[u]);
        #pragma unroll
        for (int u = 0; u < 8; ++u) {
            const __half2* h = (const __half2*)&rv[u];
            float2 f0 = __half22float2(h[0]), f1 = __half22float2(h[1]);
            float2 f2 = __half22float2(h[2]), f3 = __half22float2(h[3]);
            a[0] += f0.x; a[1] += f0.y; a[2] += f1.x; a[3] += f1.y;
            a[4] += f2.x; a[5] += f2.y; a[6] += f3.x; a[7] += f3.y;
        }
    }
    if (j0 + 4 <= e) {                        // exact 4 edges
        int c[4];
        #pragma unroll
        for (int u = 0; u < 4; ++u) c[u] = cols[j0 + u];
        float4 rv[4];
        #pragma unroll
        for (int u = 0; u < 4; ++u) rv[u] = *(const float4*)(sb + (size_t)(unsigned)c[u]);
        #pragma unroll
        for (int u = 0; u < 4; ++u) {
            const __half2* h = (const __half2*)&rv[u];
            float2 f0 = __half22float2(h[0]), f1 = __half22float2(h[1]);
            float2 f2 = __half22float2(h[2]), f3 = __half22float2(h[3]);
            a[0] += f0.x; a[1] += f0.y; a[2] += f1.x; a[3] += f1.y;
            a[4] += f2.x; a[5] += f2.y; a[6] += f3.x; a[7] += f3.y;
        }
        j0 += 4;
    }
    if (j0 < e) {                             // 1-3 remaining, clamped+weighted
        int c[4]; float w[4];
        #pragma unroll
        for (int u = 0; u < 4; ++u) {
            int j = j0 + u;
            c[u] = cols[min(j, e - 1)];
            w[u] = (j < e) ? 1.f : 0.f;
        }
        float4 rv[4];
        #pragma unroll
        for (int u = 0; u < 4; ++u) rv[u] = *(const float4*)(sb + (size_t)(unsigned)c[u]);
        #pragma unroll
        for (int u = 0; u < 4; ++u) {
            const __half2* h = (const __half2*)&rv[u];
            float2 f0 = __half22float2(h[0]), f1 = __half22float2(h[1]);
            float2 f2 = __half22float2(h[2]), f3 = __half22float2(h[3]);
            a[0] = fmaf(w[u], f0.x, a[0]); a[1] = fmaf(w[u], f0.y, a[1]);
            a[2] = fmaf(w[u], f1.x, a[2]); a[3] = fmaf(w[u], f1.y, a[3]);
            a[4] = fmaf(w[u], f2.x, a[4]); a[5] = fmaf(w[u], f2.y, a[5]);
            a[6] = fmaf(w[u], f3.x, a[6]); a[7] = fmaf(w[u], f3.y, a[7]);
        }
    }
    if (e > s) {
        float d = dsq[r];
        float4 ov;
        __half2* op = (__half2*)&ov;
        op[0] = __floats2half2_rn(a[0] * d, a[1] * d);
        op[1] = __floats2half2_rn(a[2] * d, a[3] * d);
        op[2] = __floats2half2_rn(a[4] * d, a[5] * d);
        op[3] = __floats2half2_rn(a[6] * d, a[7] * d);
        *(float4*)((char*)dst + ((size_t)r << 7) + (l8 << 4)) = ov;
    }
}

// ---------------- fused spmv3 + X-assembly + MLP ---------------------------
__global__ void __launch_bounds__(256) k_mlp(const int* __restrict__ aux,
                                             const float* __restrict__ ratef, const float* __restrict__ genderf,
                                             const float* __restrict__ agef, const float* __restrict__ occf,
                                             const float* __restrict__ areaf, const float* __restrict__ tacc,
                                             const float* __restrict__ Xmh, const float* __restrict__ cntf,
                                             const float* __restrict__ W1, const float* __restrict__ b1,
                                             const float* __restrict__ W2, const float* __restrict__ b2,
                                             const float* __restrict__ Wo, const float* __restrict__ bo,
                                             void* __restrict__ out, const void* probe,
                                             const __half* __restrict__ embA,
                                             const int2* __restrict__ moffs, const int* __restrict__ cols,
                                             const float* __restrict__ dinv, const float* __restrict__ gsc,
                                             const int* __restrict__ uids, const int* __restrict__ iids) {
    __shared__ float sx[4][640];
    __shared__ float sh[4][64];
    int isf32 = detect_f32(probe);
    int lane = threadIdx.x & 63, w = threadIdx.x >> 6;
    int b = blockIdx.x * 4 + w;
    const int* arow = aux + (size_t)b * AUX_W;
    float* xr = sx[w];

    // --- layer-3 gather for t=b (user) and t=BATCH+b (item) ----------------
    #pragma unroll 1
    for (int which = 0; which < 2; ++which) {
        int t = which ? (BATCH + b) : b;
        int r = which ? (N_USER + iids[b]) : uids[b];
        int2 se = moffs[r];
        int s = se.x, e = se.y;
        int p = lane & 31, ep = lane >> 5;
        const char* sb = (const char*)embA + (p << 2);
        float ax = 0.f, ay = 0.f;
        int j0 = s;
        for (; j0 + 16 <= e; j0 += 16) {
            int c[8];
            #pragma unroll
            for (int u = 0; u < 8; ++u) c[u] = cols[j0 + 2 * u + ep];
            float2 v[8];
            #pragma unroll
            for (int u = 0; u < 8; ++u) v[u] = __half22float2(*(const __half2*)(sb + (size_t)(unsigned)c[u]));
            #pragma unroll
            for (int u = 0; u < 8; ++u) { ax += v[u].x; ay += v[u].y; }
        }
        if (j0 + 8 <= e) {
            int c[4];
            #pragma unroll
            for (int u = 0; u < 4; ++u) c[u] = cols[j0 + 2 * u + ep];
            float2 v[4];
            #pragma unroll
            for (int u = 0; u < 4; ++u) v[u] = __half22float2(*(const __half2*)(sb + (size_t)(unsigned)c[u]));
            #pragma unroll
            for (int u = 0; u < 4; ++u) { ax += v[u].x; ay += v[u].y; }
            j0 += 8;
        }
        if (j0 + 4 <= e) {
            int c0 = cols[j0 + ep], c1 = cols[j0 + 2 + ep];
            float2 v0 = __half22float2(*(const __half2*)(sb + (size_t)(unsigned)c0));
            float2 v1 = __half22float2(*(const __half2*)(sb + (size_t)(unsigned)c1));
            ax += v0.x + v1.x; ay += v0.y + v1.y;
            j0 += 4;
        }
        if (j0 < e) {
            int j1 = j0 + ep, j2 = j0 + 2 + ep;
            int c0 = cols[min(j1, e - 1)], c1 = cols[min(j2, e - 1)];
            float w0 = (j1 < e) ? 1.f : 0.f, w1 = (j2 < e) ? 1.f : 0.f;
            float2 v0 = __half22float2(*(const __half2*)(sb + (size_t)(unsigned)c0));
            float2 v1 = __half22float2(*(const __half2*)(sb + (size_t)(unsigned)c1));
            ax = fmaf(w0, v0.x, ax); ay = fmaf(w0, v0.y, ay);
            ax = fmaf(w1, v1.x, ax); ay = fmaf(w1, v1.y, ay);
        }
        ax += __shfl_xor(ax, 32);
        ay += __shfl_xor(ay, 32);
        if (ep == 0) {
            float s0 = tacc[(size_t)t * 64 + (p << 1)];
            float s1 = tacc[(size_t)t * 64 + (p << 1) + 1];
            if (e > s) {                      // deg>0 guard: embA[r] valid only then
                float2 self = __half22float2(*(const __half2*)((const char*)embA + ((size_t)r << 7) + (p << 2)));
                float di = dinv[r], g = gsc[r];
                s0 += di * ax + g * self.x;
                s1 += di * ay + g * self.y;
            }
            xr[512 + (which << 6) + (p << 1)]     = s0 * 0.25f;
            xr[512 + (which << 6) + (p << 1) + 1] = s1 * 0.25f;
        }
    }

    // --- X assembly + MLP --------------------------------------------------
    xr[0   + lane] = ratef[arow[0] * 64 + lane];
    xr[64  + lane] = Xmh[((size_t)0 * BATCH + b) * 64 + lane] / cntf[0 * BATCH + b];
    xr[128 + lane] = Xmh[((size_t)1 * BATCH + b) * 64 + lane] / cntf[1 * BATCH + b];
    xr[192 + lane] = Xmh[((size_t)2 * BATCH + b) * 64 + lane] / cntf[2 * BATCH + b];
    xr[256 + lane] = genderf[arow[10242] * 64 + lane];
    xr[320 + lane] = agef[arow[10243] * 64 + lane];
    xr[384 + lane] = occf[arow[10244] * 64 + lane];
    xr[448 + lane] = areaf[arow[10245] * 64 + lane];
    float acc = b1[lane];
    #pragma unroll 8
    for (int k = 0; k < 640; ++k) acc += xr[k] * W1[(size_t)k * 64 + lane];
    float h1 = fmaxf(acc, 0.f);
    sh[w][lane] = h1;
    float acc2 = b2[lane];
    #pragma unroll 8
    for (int j = 0; j < 64; ++j) acc2 += sh[w][j] * W2[(size_t)j * 64 + lane];
    float h2 = fmaxf(acc2, 0.f);
    float p = h2 * Wo[lane];
    #pragma unroll
    for (int off = 32; off; off >>= 1) p += __shfl_down(p, off);
    if (lane == 0) {
        float r = p + bo[0];
        if (isf32) ((float*)out)[b] = r;
        else       ((__hip_bfloat16*)out)[b] = __float2bfloat16(r);
    }
}

extern "C" void kernel_launch(void* const* d_in, const int* in_sizes, int n_in,
                              void* d_out, int out_size, void* d_ws, size_t ws_size,
                              hipStream_t stream) {
    const int* aux  = (const int*)d_in[0];
    const int* uids = (const int*)d_in[1];
    const int* iids = (const int*)d_in[2];
    const int* grow = (const int*)d_in[3];
    const int* gcol = (const int*)d_in[4];

    char* p = (char*)d_ws;
    auto alloc = [&](size_t bytes) -> char* {
        char* r = p;
        p += (bytes + 255) / 256 * 256;
        return r;
    };
    // zero-region (one hipMemsetAsync): bucket_tot, Xmh, cntf, moffs2
    int*   bucket_tot  = (int*)alloc(512 * 4);
    float* Xmh         = (float*)alloc((size_t)3 * BATCH * 64 * 4);
    float* cntf        = (float*)alloc((size_t)3 * BATCH * 4);
    int2*  moffs2      = (int2*)alloc((size_t)180224 * 8);
    char*  zero_end    = p;
    int*   bucket_base = (int*)alloc(512 * 4);
    int*   bucketcur   = (int*)alloc(512 * 4);
    int2*  moffs       = (int2*)alloc((size_t)180224 * 8);
    float* dinv        = (float*)alloc((size_t)180224 * 4);
    float* dsq         = (float*)alloc((size_t)180224 * 4);
    float* gsc         = (float*)alloc((size_t)180224 * 4);
    int*   binned      = (int*)alloc((size_t)E2 * 4);
    int*   cols        = (int*)alloc((size_t)E2 * 4);
    __half* embH       = (__half*)alloc((size_t)N_NODES * 64 * 2);
    __half* embA       = (__half*)alloc((size_t)N_NODES * 64 * 2);
    __half* embB       = (__half*)alloc((size_t)N_NODES * 64 * 2);
    float* tacc        = (float*)alloc((size_t)2048 * 64 * 4);
    unsigned short* WtG = (unsigned short*)alloc((size_t)KP_G * 64 * 2);
    unsigned short* WtD = (unsigned short*)alloc((size_t)KP_D * 64 * 2);
    unsigned short* WtA = (unsigned short*)alloc((size_t)KP_A * 64 * 2);
    float* ratef   = (float*)alloc(384 * 4);
    float* genderf = (float*)alloc(128 * 4);
    float* agef    = (float*)alloc(448 * 4);
    float* occf    = (float*)alloc(1344 * 4);
    float* areaf   = (float*)alloc((size_t)217728 * 4);
    float* fc1W    = (float*)alloc((size_t)40960 * 4);
    float* fc1b    = (float*)alloc(64 * 4);
    float* fc2W    = (float*)alloc(4096 * 4);
    float* fc2b    = (float*)alloc(64 * 4);
    float* outW    = (float*)alloc(64 * 4);
    float* outb    = (float*)alloc(4);

    const void* probe = d_in[14];   // user_rel, for inline dtype detect

    // 0. zero accumulators (single contiguous region, DMA)
    hipMemsetAsync(bucket_tot, 0, (size_t)(zero_end - (char*)bucket_tot), stream);

    // 1. fused prep: bucket counts (first) + table cvt + Wt pack
    CvtBatch cb;
    int blk = 0, si = 0;
    auto addseg = [&](const void* s, float* d, int n) {
        cb.seg[si].src = s; cb.seg[si].dst = d; cb.seg[si].n = n; cb.seg[si].blk0 = blk;
        blk += (n + 255) / 256; ++si;
    };
    addseg(d_in[6],  ratef,   384);
    addseg(d_in[10], genderf, 128);
    addseg(d_in[11], agef,    448);
    addseg(d_in[12], occf,    1344);
    addseg(d_in[13], areaf,   217728);
    addseg(d_in[16], fc1W,   40960);
    addseg(d_in[17], fc1b,   64);
    addseg(d_in[18], fc2W,   4096);
    addseg(d_in[19], fc2b,   64);
    addseg(d_in[20], outW,   64);
    addseg(d_in[21], outb,   1);
    for (int i = si; i < 16; ++i) { cb.seg[i].src = nullptr; cb.seg[i].dst = nullptr; cb.seg[i].n = 0; cb.seg[i].blk0 = 0x7fffffff; }
    const int cvtBlks = blk;
    hipLaunchKernelGGL(k_prep, dim3(BCNT_BLKS + cvtBlks + WT_BLKS), dim3(256), 0, stream,
                       cb, cvtBlks, d_in[7], d_in[8], d_in[9], WtG, WtD, WtA, grow, bucket_tot, probe);

    // 2. CSR build (p1 carries mhgemm + cvt + tacc0 as overlap cargo)
    hipLaunchKernelGGL(k_bscan, dim3(1), dim3(512), 0, stream, bucket_tot, bucket_base, bucketcur);
    hipLaunchKernelGGL(k_p1, dim3(MH_BLKS + BCNT_BLKS + CVT_BLKS + 512), dim3(256), 0, stream,
                       grow, gcol, bucketcur, binned, aux, WtG, WtD, WtA, Xmh, cntf,
                       d_in[14], d_in[15], embH, tacc, uids, iids);
    hipLaunchKernelGGL(k_p2, dim3(NBKT), dim3(256), 0, stream, binned, bucket_base, cols, moffs, dinv, dsq, gsc);

    // 3. LightGCN. L1 gathers embH (f16) with per-edge dinv + mark cargo;
    //    L2 in half domain + tacc-f1 cargo; L3 fused into mlp.
    const int spmvN = N_NODES / 32;           // 8 rows/wave * 4 waves/block
    hipLaunchKernelGGL(k_spmv_w, dim3(spmvN + 512), dim3(256), 0, stream,
                       embH, embB, moffs, cols, dinv, dsq, spmvN, uids, iids, moffs2);
    hipLaunchKernelGGL(k_spmv, dim3(spmvN + 512), dim3(256), 0, stream,
                       embB, embA, moffs2, cols, dsq, spmvN, tacc, uids, iids, gsc);

    // 4. fused spmv3 + X + MLP -> out
    hipLaunchKernelGGL(k_mlp, dim3(BATCH / 4), dim3(256), 0, stream,
                       aux, ratef, genderf, agef, occf, areaf, tacc, Xmh, cntf,
                       fc1W, fc1b, fc2W, fc2b, outW, outb, d_out, probe,
                       embA, moffs, cols, dinv, gsc, uids, iids);
}

// Round 11
// 286.320 us; speedup vs baseline: 1.0087x; 1.0087x over previous
//
#include <hip/hip_runtime.h>
#include <hip/hip_bf16.h>
#include <hip/hip_fp16.h>

#define N_USER 150000
#define M_ITEM 30000
#define N_NODES 180000
#define E2 1200000
#define BATCH 1024
#define AUX_W 10246
#define KP_G 32
#define KP_D 2208
#define KP_A 8064
#define NBKT 265       // 147 user buckets (1024 rows) + 118 item buckets (256 rows)
#define WT_BLKS 2576   // ((KP_G+KP_D+KP_A)*64 + 255)/256
#define BCNT_BLKS 293  // (E2 + 4095)/4096
#define MH_BLKS 672    // 16 genre + 144 director (9 x16) + 512 actor (32 x16), K-chunk 256
#define CVT_BLKS 5625  // N_NODES*8/256 (exactly)
#define NSLICE 42      // 1 genre + 9 director + 32 actor K-partial slices

typedef __attribute__((ext_vector_type(8))) short short8;
typedef __attribute__((ext_vector_type(8))) unsigned short ushort8_t;
typedef __attribute__((ext_vector_type(4))) float f32x4;

__device__ __forceinline__ int bucket_of(int r) {
    return r < N_USER ? (r >> 10) : 147 + ((r - N_USER) >> 8);
}

// inline dtype detect (wave-uniform): bf16 data reads small; f32-as-bf16 huge.
__device__ __forceinline__ int detect_f32(const void* probe) {
    float v = __bfloat162float(((const __hip_bfloat16*)probe)[threadIdx.x & 63]);
    unsigned long long m = __ballot(!(fabsf(v) < 1000.0f));
    return __popcll(m) > 8;
}

// ---------------- fused prep: bucket counts + table cvt + Wt pack ----------
// R6: count blocks FIRST (long pole overlaps light cvt/WT blocks).
struct CvtSeg { const void* src; float* dst; int n; int blk0; };
struct CvtBatch { CvtSeg seg[16]; };

__global__ void __launch_bounds__(256) k_prep(CvtBatch cb, int cvtBlks,
                                              const void* Wg, const void* Wd, const void* Wa,
                                              unsigned short* WtG, unsigned short* WtD, unsigned short* WtA,
                                              const int* __restrict__ grow, int* __restrict__ bucket_tot,
                                              const void* probe) {
    int blk = blockIdx.x, tid = threadIdx.x;
    if (blk < BCNT_BLKS) {                     // --- bucket counts (first: long pole)
        __shared__ int h[NBKT];
        for (int i = tid; i < NBKT; i += 256) h[i] = 0;
        __syncthreads();
        int idx0 = blk * 4096;
        #pragma unroll
        for (int k = 0; k < 16; ++k) {
            int i = idx0 + k * 256 + tid;
            if (i < E2) atomicAdd(&h[bucket_of(grow[i])], 1);
        }
        __syncthreads();
        for (int i = tid; i < NBKT; i += 256) if (h[i]) atomicAdd(&bucket_tot[i], h[i]);
        return;
    }
    if (blk < BCNT_BLKS + cvtBlks) {           // --- small-table f32 conversion
        int isf32 = detect_f32(probe);
        int cblk = blk - BCNT_BLKS;
        int si = 0;
        #pragma unroll
        for (int i = 0; i < 16; ++i) if (cblk >= cb.seg[i].blk0) si = i;
        const CvtSeg sg = cb.seg[si];
        int i = (cblk - sg.blk0) * 256 + tid;
        if (i >= sg.n) return;
        if (isf32) sg.dst[i] = ((const float*)sg.src)[i];
        else       sg.dst[i] = __bfloat162float(((const __hip_bfloat16*)sg.src)[i]);
        return;
    }
    {                                          // --- Wt B-fragment pack
        int isf32 = detect_f32(probe);
        int t = (blk - BCNT_BLKS - cvtBlks) * 256 + tid;
        if (t >= (KP_G + KP_D + KP_A) * 64) return;
        int kp = t >> 6, n = t & 63;
        int k, K; const void* src; unsigned short* dst;
        if (kp < KP_G)              { k = kp;               K = 25;   src = Wg; dst = WtG; }
        else if (kp < KP_G + KP_D)  { k = kp - KP_G;        K = 2186; src = Wd; dst = WtD; }
        else                        { k = kp - KP_G - KP_D; K = 8030; src = Wa; dst = WtA; }
        unsigned short v = 0;
        if (k < K) {
            if (isf32) {
                __hip_bfloat16 h = __float2bfloat16(((const float*)src)[(size_t)k * 64 + n]);
                v = *(unsigned short*)&h;
            } else {
                v = ((const unsigned short*)src)[(size_t)k * 64 + n];
            }
        }
        dst[(((size_t)(k >> 5) * 64 + n) * 4 + ((k >> 3) & 3)) * 8 + (k & 7)] = v;
    }
}

// ---------------- bucket scan ----------------
__global__ void __launch_bounds__(512) k_bscan(const int* __restrict__ bucket_tot,
                                               int* __restrict__ bucket_base,
                                               int* __restrict__ bucketcur) {
    __shared__ int s[512];
    int tid = threadIdx.x;
    s[tid] = (tid < NBKT) ? bucket_tot[tid] : 0;
    __syncthreads();
    for (int off = 1; off < 512; off <<= 1) {
        int v = (tid >= off) ? s[tid - off] : 0;
        __syncthreads();
        s[tid] += v;
        __syncthreads();
    }
    int excl = tid ? s[tid - 1] : 0;
    bucket_base[tid] = excl;                 // bucket_base[NBKT] = E2
    if (tid < NBKT) bucketcur[tid] = excl;
}

// ---------------- mhgemm device body (R10: private K-partial slices) -------
// R10: the 2.75M global atomicAdds to a shared Xmh (16/thread, ~14-way
// per-address contention) were memory-side RMWs (R6 mechanism) -- ~11MB of
// WRITE traffic and a large chunk of p1's time. Each (slice,rb) tile is now
// PRIVATE to one block: plain stores, no zeroing needed (fully written).
// k_mlp sums the 1/9/32 partial slices per row. cntf atomics stay (43K).
__device__ void mhgemm_body(int blk, const int* __restrict__ aux,
                            const unsigned short* __restrict__ WtG,
                            const unsigned short* __restrict__ WtD,
                            const unsigned short* __restrict__ WtA,
                            float* __restrict__ Xpart, float* __restrict__ cntf) {
    int seg, rb, k0, klen, Kseg, auxoff, slice;
    const unsigned short* Wt;
    if (blk < 16)       { seg = 0; rb = blk;                      k0 = 0;              klen = 25;                  Kseg = 25;   auxoff = 1;    Wt = WtG; slice = 0; }
    else if (blk < 160) { int t = blk - 16;  seg = 1; rb = t & 15; k0 = (t >> 4) * 256; klen = min(256, 2186 - k0); Kseg = 2186; auxoff = 26;   Wt = WtD; slice = 1 + (t >> 4); }
    else                { int t = blk - 160; seg = 2; rb = t & 15; k0 = (t >> 4) * 256; klen = min(256, 8030 - k0); Kseg = 8030; auxoff = 2212; Wt = WtA; slice = 10 + (t >> 4); }
    int lane = threadIdx.x & 63, wave = threadIdx.x >> 6;
    int m = lane & 15, quad = lane >> 4;
    int row = rb * 64 + wave * 16 + m;
    const int* arow = aux + (size_t)row * AUX_W + auxoff;

    f32x4 acc0 = {0.f,0.f,0.f,0.f}, acc1 = acc0, acc2 = acc0, acc3 = acc0;
    int isum = 0;
    int nchunk = (klen + 31) >> 5;
    int pa[8], na[8];
    auto lda = [&](int kci, int (&A)[8]) {
        int kb = k0 + kci * 32 + quad * 8;
        if (kb + 8 <= Kseg) {
            #pragma unroll
            for (int j = 0; j < 8; ++j) A[j] = arow[kb + j];
        } else {
            #pragma unroll
            for (int j = 0; j < 8; ++j) A[j] = (kb + j < Kseg) ? arow[kb + j] : 0;
        }
    };
    lda(0, pa);
    for (int kci = 0; kci < nchunk; ++kci) {
        if (kci + 1 < nchunk) lda(kci + 1, na);   // prefetch next chunk's aux
        union { unsigned u[4]; short8 s; } af;
        af.u[0] = (unsigned)pa[0] * 16256u + (unsigned)pa[1] * 0x3F800000u;
        af.u[1] = (unsigned)pa[2] * 16256u + (unsigned)pa[3] * 0x3F800000u;
        af.u[2] = (unsigned)pa[4] * 16256u + (unsigned)pa[5] * 0x3F800000u;
        af.u[3] = (unsigned)pa[6] * 16256u + (unsigned)pa[7] * 0x3F800000u;
        isum += pa[0] + pa[1] + pa[2] + pa[3] + pa[4] + pa[5] + pa[6] + pa[7];
        size_t kcg = (size_t)(k0 >> 5) + kci;
        const unsigned short* bp = Wt + ((kcg * 64 + m) * 4 + quad) * 8;
        short8 b0 = *(const short8*)(bp);
        short8 b1 = *(const short8*)(bp + 512);
        short8 b2 = *(const short8*)(bp + 1024);
        short8 b3 = *(const short8*)(bp + 1536);
        acc0 = __builtin_amdgcn_mfma_f32_16x16x32_bf16(af.s, b0, acc0, 0, 0, 0);
        acc1 = __builtin_amdgcn_mfma_f32_16x16x32_bf16(af.s, b1, acc1, 0, 0, 0);
        acc2 = __builtin_amdgcn_mfma_f32_16x16x32_bf16(af.s, b2, acc2, 0, 0, 0);
        acc3 = __builtin_amdgcn_mfma_f32_16x16x32_bf16(af.s, b3, acc3, 0, 0, 0);
        #pragma unroll
        for (int j = 0; j < 8; ++j) pa[j] = na[j];
    }
    float asum = (float)isum;
    asum += __shfl_xor(asum, 16);
    asum += __shfl_xor(asum, 32);
    if (quad == 0) atomicAdd(&cntf[seg * BATCH + row], asum);
    float* xbase = Xpart + ((size_t)slice * BATCH + rb * 64 + wave * 16 + quad * 4) * 64;
    #pragma unroll
    for (int reg = 0; reg < 4; ++reg) {
        float* xr = xbase + (size_t)reg * 64;
        xr[ 0 + m] = acc0[reg];
        xr[16 + m] = acc1[reg];
        xr[32 + m] = acc2[reg];
        xr[48 + m] = acc3[reg];
    }
}

// ---------------- P1: mhgemm + binning + unscaled cvt + tacc0 --------------
// R9: binned compacted to int (bucket implicit in position):
//   user bucket: (c<<10)|(r&1023); item bucket: (c<<8)|((r-N_USER)&255).
// Blocks: [0,672) mhgemm; [672,965) binning; [965,6590) cvt; [6590,7102) tacc0.
__global__ void __launch_bounds__(256) k_p1(const int* __restrict__ grow, const int* __restrict__ gcol,
                                            int* __restrict__ bucketcur, int* __restrict__ binned,
                                            const int* __restrict__ aux,
                                            const unsigned short* __restrict__ WtG,
                                            const unsigned short* __restrict__ WtD,
                                            const unsigned short* __restrict__ WtA,
                                            float* __restrict__ Xpart, float* __restrict__ cntf,
                                            const void* rawU, const void* rawI,
                                            __half* __restrict__ embH,
                                            float* __restrict__ tacc,
                                            const int* __restrict__ uids, const int* __restrict__ iids) {
    int blk = blockIdx.x;
    if (blk < MH_BLKS) {
        mhgemm_body(blk, aux, WtG, WtD, WtA, Xpart, cntf);
        return;
    }
    if (blk < MH_BLKS + BCNT_BLKS) {          // --- edge binning (compact enc)
        __shared__ int h1[NBKT], base1[NBKT];
        int tid = threadIdx.x;
        for (int i = tid; i < NBKT; i += 256) h1[i] = 0;
        __syncthreads();
        int idx0 = (blk - MH_BLKS) * 4096;
        int r[16], c[16];
        #pragma unroll
        for (int k = 0; k < 16; ++k) {
            int i = idx0 + k * 256 + tid;
            if (i < E2) {
                r[k] = grow[i]; c[k] = gcol[i];
                atomicAdd(&h1[bucket_of(r[k])], 1);
            } else r[k] = -1;
        }
        __syncthreads();
        for (int i = tid; i < NBKT; i += 256) {
            base1[i] = h1[i] ? atomicAdd(&bucketcur[i], h1[i]) : 0;
            h1[i] = 0;
        }
        __syncthreads();
        #pragma unroll
        for (int k = 0; k < 16; ++k) {
            if (r[k] >= 0) {
                int b = bucket_of(r[k]);
                int p = base1[b] + atomicAdd(&h1[b], 1);
                int enc = (r[k] < N_USER) ? ((c[k] << 10) | (r[k] & 1023))
                                          : ((c[k] << 8) | ((r[k] - N_USER) & 255));
                binned[p] = enc;
            }
        }
        return;
    }
    if (blk < MH_BLKS + BCNT_BLKS + CVT_BLKS) {   // --- unscaled emb cvt (16B/lane)
        int isf32 = detect_f32(rawU);
        int q = (blk - MH_BLKS - BCNT_BLKS) * 256 + threadIdx.x;  // octet (8 elems)
        int r = q >> 3;                            // CVT_BLKS*256 == N_NODES*8 exactly
        const void* src; size_t qq;
        if (r < N_USER) { src = rawU; qq = (size_t)q; }
        else            { src = rawI; qq = (size_t)q - (size_t)N_USER * 8; }
        float f[8];
        if (isf32) {
            float4 a = ((const float4*)src)[qq * 2], b = ((const float4*)src)[qq * 2 + 1];
            f[0]=a.x; f[1]=a.y; f[2]=a.z; f[3]=a.w; f[4]=b.x; f[5]=b.y; f[6]=b.z; f[7]=b.w;
        } else {
            ushort8_t u = ((const ushort8_t*)src)[qq];
            #pragma unroll
            for (int i = 0; i < 8; ++i) {
                unsigned short us = u[i];
                f[i] = __bfloat162float(*(__hip_bfloat16*)&us);
            }
        }
        ushort8_t o;
        #pragma unroll
        for (int i = 0; i < 8; ++i) {
            __half h = __float2half(f[i]);
            o[i] = *(unsigned short*)&h;
        }
        ((ushort8_t*)embH)[(size_t)q] = o;
        return;
    }
    {                                         // --- tacc0 init from RAW rows
        int isf32 = detect_f32(rawU);
        int lane = threadIdx.x & 63;
        int t = (blk - MH_BLKS - BCNT_BLKS - CVT_BLKS) * 4 + (threadIdx.x >> 6);
        const void* s; size_t ri;
        if (t < BATCH) { s = rawU; ri = (size_t)uids[t]; }
        else           { s = rawI; ri = (size_t)iids[t - BATCH]; }
        float v;
        if (isf32) v = ((const float*)s)[ri * 64 + lane];
        else       v = __bfloat162float(((const __hip_bfloat16*)s)[ri * 64 + lane]);
        tacc[(size_t)t * 64 + lane] = v;
    }
}

// ---------------- P2: per-bucket sort + packed (start,end) + factors -------
// R9: decodes compact binned entries (bucket-type known from block index).
__global__ void __launch_bounds__(256) k_p2(const int* __restrict__ binned, const int* __restrict__ bb,
                                            int* __restrict__ cols, int2* __restrict__ moffs,
                                            float* __restrict__ dinv, float* __restrict__ dsq,
                                            float* __restrict__ gsc) {
    __shared__ int h[1024];
    __shared__ int ws2[256];
    int b = blockIdx.x, tid = threadIdx.x;
    int r0, r1, shift, mask;
    if (b < 147) { r0 = b << 10; r1 = min((b + 1) << 10, N_USER); shift = 10; mask = 1023; }
    else         { r0 = N_USER + ((b - 147) << 8); r1 = min(N_USER + ((b - 146) << 8), N_NODES); shift = 8; mask = 255; }
    int s0 = bb[b], e0 = bb[b + 1];
    for (int i = tid; i < 1024; i += 256) h[i] = 0;
    __syncthreads();
    for (int j = s0 + tid; j < e0; j += 256) atomicAdd(&h[binned[j] & mask], 1);
    __syncthreads();
    int t0 = tid * 4;
    int a0 = h[t0], a1 = h[t0 + 1], a2 = h[t0 + 2], a3 = h[t0 + 3];
    ws2[tid] = a0 + a1 + a2 + a3;
    __syncthreads();
    for (int off = 1; off < 256; off <<= 1) {
        int v = (tid >= off) ? ws2[tid - off] : 0;
        __syncthreads();
        ws2[tid] += v;
        __syncthreads();
    }
    int excl = tid ? ws2[tid - 1] : 0;
    int ex[4] = { excl, excl + a0, excl + a0 + a1, excl + a0 + a1 + a2 };
    int ac[4] = { a0, a1, a2, a3 };
    #pragma unroll
    for (int i = 0; i < 4; ++i) {
        int row = r0 + t0 + i;
        if (row < r1) {
            moffs[row] = make_int2(s0 + ex[i], s0 + ex[i] + ac[i]);
            float deg = (float)ac[i];
            bool nz = deg > 0.f;
            dinv[row] = nz ? rsqrtf(deg) : 0.f;
            dsq[row]  = nz ? 1.f / deg  : 0.f;
            gsc[row]  = nz ? sqrtf(deg) : 0.f;
        }
        h[t0 + i] = ex[i];
    }
    __syncthreads();
    for (int j = s0 + tid; j < e0; j += 256) {
        int v = binned[j];
        int p = s0 + atomicAdd(&h[v & mask], 1);
        cols[p] = ((unsigned)v >> shift) << 7;   // byte offset into a 64-half row
    }
}

// ---------------- L1 SpMV: gather embH (f16) with per-edge dinv weight -----
// dst[r] = dsq[r] * sum_c dinv[c]*embH[c]. 8 rows/wave, 16B slice/lane.
// Cargo: [spmvN,+512) mark moffs2.
__global__ void __launch_bounds__(256, 4) k_spmv_w(const __half* __restrict__ src,
                                                   __half* __restrict__ dst,
                                                   const int2* __restrict__ moffs_in,
                                                   const int* __restrict__ cols,
                                                   const float* __restrict__ dinv,
                                                   const float* __restrict__ dsq,
                                                   int spmvN,
                                                   const int* __restrict__ uids, const int* __restrict__ iids,
                                                   int2* __restrict__ moffs2) {
    int tid = threadIdx.x, lane = tid & 63;
    int blk = blockIdx.x;
    if (blk >= spmvN) {                       // mark moffs2[r] for T u N(T)
        int t = (blk - spmvN) * 4 + (tid >> 6);
        int r = (t < BATCH) ? uids[t] : (N_USER + iids[t - BATCH]);
        int2 se = moffs_in[r];
        if (lane == 0) moffs2[r] = se;
        for (int j = se.x + lane; j < se.y; j += 64) {
            int c = (unsigned)cols[j] >> 7;
            moffs2[c] = moffs_in[c];          // benign dup races: same value
        }
        return;
    }
    int wid8 = blk * 4 + (tid >> 6);          // wave id; 8 rows per wave
    int g = lane >> 3, l8 = lane & 7;
    int r = wid8 * 8 + g;                     // r < N_NODES exactly
    int2 se = moffs_in[r];
    int s = se.x, e = se.y;
    const char* sb = (const char*)src + (l8 << 4);   // 16B slice of gathered row
    float a[8] = {0.f,0.f,0.f,0.f,0.f,0.f,0.f,0.f};
    int j0 = s;
    for (; j0 + 8 <= e; j0 += 8) {            // 8 edges/iter (item rows)
        int c[8]; float w[8];
        #pragma unroll
        for (int u = 0; u < 8; ++u) { c[u] = cols[j0 + u]; w[u] = dinv[(unsigned)c[u] >> 7]; }
        float4 rv[8];
        #pragma unroll
        for (int u = 0; u < 8; ++u) rv[u] = *(const float4*)(sb + (size_t)(unsigned)c[u]);
        #pragma unroll
        for (int u = 0; u < 8; ++u) {
            const __half2* h = (const __half2*)&rv[u];
            float2 f0 = __half22float2(h[0]), f1 = __half22float2(h[1]);
            float2 f2 = __half22float2(h[2]), f3 = __half22float2(h[3]);
            a[0] = fmaf(w[u], f0.x, a[0]); a[1] = fmaf(w[u], f0.y, a[1]);
            a[2] = fmaf(w[u], f1.x, a[2]); a[3] = fmaf(w[u], f1.y, a[3]);
            a[4] = fmaf(w[u], f2.x, a[4]); a[5] = fmaf(w[u], f2.y, a[5]);
            a[6] = fmaf(w[u], f3.x, a[6]); a[7] = fmaf(w[u], f3.y, a[7]);
        }
    }
    if (j0 + 4 <= e) {                        // exact 4 edges
        int c[4]; float w[4];
        #pragma unroll
        for (int u = 0; u < 4; ++u) { c[u] = cols[j0 + u]; w[u] = dinv[(unsigned)c[u] >> 7]; }
        float4 rv[4];
        #pragma unroll
        for (int u = 0; u < 4; ++u) rv[u] = *(const float4*)(sb + (size_t)(unsigned)c[u]);
        #pragma unroll
        for (int u = 0; u < 4; ++u) {
            const __half2* h = (const __half2*)&rv[u];
            float2 f0 = __half22float2(h[0]), f1 = __half22float2(h[1]);
            float2 f2 = __half22float2(h[2]), f3 = __half22float2(h[3]);
            a[0] = fmaf(w[u], f0.x, a[0]); a[1] = fmaf(w[u], f0.y, a[1]);
            a[2] = fmaf(w[u], f1.x, a[2]); a[3] = fmaf(w[u], f1.y, a[3]);
            a[4] = fmaf(w[u], f2.x, a[4]); a[5] = fmaf(w[u], f2.y, a[5]);
            a[6] = fmaf(w[u], f3.x, a[6]); a[7] = fmaf(w[u], f3.y, a[7]);
        }
        j0 += 4;
    }
    if (j0 < e) {                             // 1-3 remaining, clamped+weighted
        int c[4]; float w[4];
        #pragma unroll
        for (int u = 0; u < 4; ++u) {
            int j = j0 + u;
            c[u] = cols[min(j, e - 1)];
            w[u] = (j < e) ? dinv[(unsigned)c[u] >> 7] : 0.f;
        }
        float4 rv[4];
        #pragma unroll
        for (int u = 0; u < 4; ++u) rv[u] = *(const float4*)(sb + (size_t)(unsigned)c[u]);
        #pragma unroll
        for (int u = 0; u < 4; ++u) {
            const __half2* h = (const __half2*)&rv[u];
            float2 f0 = __half22float2(h[0]), f1 = __half22float2(h[1]);
            float2 f2 = __half22float2(h[2]), f3 = __half22float2(h[3]);
            a[0] = fmaf(w[u], f0.x, a[0]); a[1] = fmaf(w[u], f0.y, a[1]);
            a[2] = fmaf(w[u], f1.x, a[2]); a[3] = fmaf(w[u], f1.y, a[3]);
            a[4] = fmaf(w[u], f2.x, a[4]); a[5] = fmaf(w[u], f2.y, a[5]);
            a[6] = fmaf(w[u], f3.x, a[6]); a[7] = fmaf(w[u], f3.y, a[7]);
        }
    }
    if (e > s) {
        float d = dsq[r];
        float4 ov;
        __half2* op = (__half2*)&ov;
        op[0] = __floats2half2_rn(a[0] * d, a[1] * d);
        op[1] = __floats2half2_rn(a[2] * d, a[3] * d);
        op[2] = __floats2half2_rn(a[4] * d, a[5] * d);
        op[3] = __floats2half2_rn(a[6] * d, a[7] * d);
        *(float4*)((char*)dst + ((size_t)r << 7) + (l8 << 4)) = ov;
    }
}

// ---------------- L2 SpMV (half domain) + tacc-f1 cargo --------------------
__global__ void __launch_bounds__(256, 4) k_spmv(const __half* __restrict__ src, __half* __restrict__ dst,
                                                 const int2* __restrict__ moffs_in, const int* __restrict__ cols,
                                                 const float* __restrict__ dsq,
                                                 int spmvN, float* __restrict__ tacc,
                                                 const int* __restrict__ uids, const int* __restrict__ iids,
                                                 const float* __restrict__ gsc) {
    int tid = threadIdx.x, lane = tid & 63;
    int blk = blockIdx.x;
    if (blk >= spmvN) {                       // tacc += gsc[r]*src[r] (deg>0 guard)
        int t = (blk - spmvN) * 4 + (tid >> 6);
        int r = (t < BATCH) ? uids[t] : (N_USER + iids[t - BATCH]);
        float g = gsc[r];
        float h = __half2float(src[(size_t)r * 64 + lane]);
        tacc[(size_t)t * 64 + lane] += (g > 0.f) ? h * g : 0.f;
        return;
    }
    int wid8 = blk * 4 + (tid >> 6);          // wave id; 8 rows per wave
    int g = lane >> 3, l8 = lane & 7;
    int r = wid8 * 8 + g;
    int2 se = moffs_in[r];
    int s = se.x, e = se.y;
    const char* sb = (const char*)src + (l8 << 4);   // 16B slice of gathered row
    float a[8] = {0.f,0.f,0.f,0.f,0.f,0.f,0.f,0.f};
    int j0 = s;
    for (; j0 + 8 <= e; j0 += 8) {            // 8 edges/iter (item rows)
        int c[8];
        #pragma unroll
        for (int u = 0; u < 8; ++u) c[u] = cols[j0 + u];
        float4 rv[8];
        #pragma unroll
        for (int u = 0; u < 8; ++u) rv[u] = *(const float4*)(sb + (size_t)(unsigned)c[u]);
        #pragma unroll
        for (int u = 0; u < 8; ++u) {
            const __half2* h = (const __half2*)&rv[u];
            float2 f0 = __half22float2(h[0]), f1 = __half22float2(h[1]);
            float2 f2 = __half22float2(h[2]), f3 = __half22float2(h[3]);
            a[0] += f0.x; a[1] += f0.y; a[2] += f1.x; a[3] += f1.y;
            a[4] += f2.x; a[5] += f2.y; a[6] += f3.x; a[7] += f3.y;
        }
    }
    if (j0 + 4 <= e) {                        // exact 4 edges
        int c[4];
        #pragma unroll
        for (int u = 0; u < 4; ++u) c[u] = cols[j0 + u];
        float4 rv[4];
        #pragma unroll
        for (int u = 0; u < 4; ++u) rv[u] = *(const float4*)(sb + (size_t)(unsigned)c[u]);
        #pragma unroll
        for (int u = 0; u < 4; ++u) {
            const __half2* h = (const __half2*)&rv[u];
            float2 f0 = __half22float2(h[0]), f1 = __half22float2(h[1]);
            float2 f2 = __half22float2(h[2]), f3 = __half22float2(h[3]);
            a[0] += f0.x; a[1] += f0.y; a[2] += f1.x; a[3] += f1.y;
            a[4] += f2.x; a[5] += f2.y; a[6] += f3.x; a[7] += f3.y;
        }
        j0 += 4;
    }
    if (j0 < e) {                             // 1-3 remaining, clamped+weighted
        int c[4]; float w[4];
        #pragma unroll
        for (int u = 0; u < 4; ++u) {
            int j = j0 + u;
            c[u] = cols[min(j, e - 1)];
            w[u] = (j < e) ? 1.f : 0.f;
        }
        float4 rv[4];
        #pragma unroll
        for (int u = 0; u < 4; ++u) rv[u] = *(const float4*)(sb + (size_t)(unsigned)c[u]);
        #pragma unroll
        for (int u = 0; u < 4; ++u) {
            const __half2* h = (const __half2*)&rv[u];
            float2 f0 = __half22float2(h[0]), f1 = __half22float2(h[1]);
            float2 f2 = __half22float2(h[2]), f3 = __half22float2(h[3]);
            a[0] = fmaf(w[u], f0.x, a[0]); a[1] = fmaf(w[u], f0.y, a[1]);
            a[2] = fmaf(w[u], f1.x, a[2]); a[3] = fmaf(w[u], f1.y, a[3]);
            a[4] = fmaf(w[u], f2.x, a[4]); a[5] = fmaf(w[u], f2.y, a[5]);
            a[6] = fmaf(w[u], f3.x, a[6]); a[7] = fmaf(w[u], f3.y, a[7]);
        }
    }
    if (e > s) {
        float d = dsq[r];
        float4 ov;
        __half2* op = (__half2*)&ov;
        op[0] = __floats2half2_rn(a[0] * d, a[1] * d);
        op[1] = __floats2half2_rn(a[2] * d, a[3] * d);
        op[2] = __floats2half2_rn(a[4] * d, a[5] * d);
        op[3] = __floats2half2_rn(a[6] * d, a[7] * d);
        *(float4*)((char*)dst + ((size_t)r << 7) + (l8 << 4)) = ov;
    }
}

// ---------------- fused spmv3 + X-assembly + MLP ---------------------------
// R10: sums mhgemm's private K-partial slices (1 genre + 9 dir + 32 actor).
__global__ void __launch_bounds__(256) k_mlp(const int* __restrict__ aux,
                                             const float* __restrict__ ratef, const float* __restrict__ genderf,
                                             const float* __restrict__ agef, const float* __restrict__ occf,
                                             const float* __restrict__ areaf, const float* __restrict__ tacc,
                                             const float* __restrict__ Xpart, const float* __restrict__ cntf,
                                             const float* __restrict__ W1, const float* __restrict__ b1,
                                             const float* __restrict__ W2, const float* __restrict__ b2,
                                             const float* __restrict__ Wo, const float* __restrict__ bo,
                                             void* __restrict__ out, const void* probe,
                                             const __half* __restrict__ embA,
                                             const int2* __restrict__ moffs, const int* __restrict__ cols,
                                             const float* __restrict__ dinv, const float* __restrict__ gsc,
                                             const int* __restrict__ uids, const int* __restrict__ iids) {
    __shared__ float sx[4][640];
    __shared__ float sh[4][64];
    int isf32 = detect_f32(probe);
    int lane = threadIdx.x & 63, w = threadIdx.x >> 6;
    int b = blockIdx.x * 4 + w;
    const int* arow = aux + (size_t)b * AUX_W;
    float* xr = sx[w];

    // --- layer-3 gather for t=b (user) and t=BATCH+b (item) ----------------
    #pragma unroll 1
    for (int which = 0; which < 2; ++which) {
        int t = which ? (BATCH + b) : b;
        int r = which ? (N_USER + iids[b]) : uids[b];
        int2 se = moffs[r];
        int s = se.x, e = se.y;
        int p = lane & 31, ep = lane >> 5;
        const char* sb = (const char*)embA + (p << 2);
        float ax = 0.f, ay = 0.f;
        int j0 = s;
        for (; j0 + 16 <= e; j0 += 16) {
            int c[8];
            #pragma unroll
            for (int u = 0; u < 8; ++u) c[u] = cols[j0 + 2 * u + ep];
            float2 v[8];
            #pragma unroll
            for (int u = 0; u < 8; ++u) v[u] = __half22float2(*(const __half2*)(sb + (size_t)(unsigned)c[u]));
            #pragma unroll
            for (int u = 0; u < 8; ++u) { ax += v[u].x; ay += v[u].y; }
        }
        if (j0 + 8 <= e) {
            int c[4];
            #pragma unroll
            for (int u = 0; u < 4; ++u) c[u] = cols[j0 + 2 * u + ep];
            float2 v[4];
            #pragma unroll
            for (int u = 0; u < 4; ++u) v[u] = __half22float2(*(const __half2*)(sb + (size_t)(unsigned)c[u]));
            #pragma unroll
            for (int u = 0; u < 4; ++u) { ax += v[u].x; ay += v[u].y; }
            j0 += 8;
        }
        if (j0 + 4 <= e) {
            int c0 = cols[j0 + ep], c1 = cols[j0 + 2 + ep];
            float2 v0 = __half22float2(*(const __half2*)(sb + (size_t)(unsigned)c0));
            float2 v1 = __half22float2(*(const __half2*)(sb + (size_t)(unsigned)c1));
            ax += v0.x + v1.x; ay += v0.y + v1.y;
            j0 += 4;
        }
        if (j0 < e) {
            int j1 = j0 + ep, j2 = j0 + 2 + ep;
            int c0 = cols[min(j1, e - 1)], c1 = cols[min(j2, e - 1)];
            float w0 = (j1 < e) ? 1.f : 0.f, w1 = (j2 < e) ? 1.f : 0.f;
            float2 v0 = __half22float2(*(const __half2*)(sb + (size_t)(unsigned)c0));
            float2 v1 = __half22float2(*(const __half2*)(sb + (size_t)(unsigned)c1));
            ax = fmaf(w0, v0.x, ax); ay = fmaf(w0, v0.y, ay);
            ax = fmaf(w1, v1.x, ax); ay = fmaf(w1, v1.y, ay);
        }
        ax += __shfl_xor(ax, 32);
        ay += __shfl_xor(ay, 32);
        if (ep == 0) {
            float s0 = tacc[(size_t)t * 64 + (p << 1)];
            float s1 = tacc[(size_t)t * 64 + (p << 1) + 1];
            if (e > s) {                      // deg>0 guard: embA[r] valid only then
                float2 self = __half22float2(*(const __half2*)((const char*)embA + ((size_t)r << 7) + (p << 2)));
                float di = dinv[r], g = gsc[r];
                s0 += di * ax + g * self.x;
                s1 += di * ay + g * self.y;
            }
            xr[512 + (which << 6) + (p << 1)]     = s0 * 0.25f;
            xr[512 + (which << 6) + (p << 1) + 1] = s1 * 0.25f;
        }
    }

    // --- X assembly (sum K-partial slices) + MLP ---------------------------
    {
        float g0 = Xpart[((size_t)0 * BATCH + b) * 64 + lane];
        float s1 = 0.f;
        #pragma unroll
        for (int kc = 0; kc < 9; ++kc)  s1 += Xpart[((size_t)(1 + kc) * BATCH + b) * 64 + lane];
        float s2 = 0.f;
        #pragma unroll
        for (int kc = 0; kc < 32; ++kc) s2 += Xpart[((size_t)(10 + kc) * BATCH + b) * 64 + lane];
        xr[64  + lane] = g0 / cntf[0 * BATCH + b];
        xr[128 + lane] = s1 / cntf[1 * BATCH + b];
        xr[192 + lane] = s2 / cntf[2 * BATCH + b];
    }
    xr[0   + lane] = ratef[arow[0] * 64 + lane];
    xr[256 + lane] = genderf[arow[10242] * 64 + lane];
    xr[320 + lane] = agef[arow[10243] * 64 + lane];
    xr[384 + lane] = occf[arow[10244] * 64 + lane];
    xr[448 + lane] = areaf[arow[10245] * 64 + lane];
    float acc = b1[lane];
    #pragma unroll 8
    for (int k = 0; k < 640; ++k) acc += xr[k] * W1[(size_t)k * 64 + lane];
    float h1 = fmaxf(acc, 0.f);
    sh[w][lane] = h1;
    float acc2 = b2[lane];
    #pragma unroll 8
    for (int j = 0; j < 64; ++j) acc2 += sh[w][j] * W2[(size_t)j * 64 + lane];
    float h2 = fmaxf(acc2, 0.f);
    float p = h2 * Wo[lane];
    #pragma unroll
    for (int off = 32; off; off >>= 1) p += __shfl_down(p, off);
    if (lane == 0) {
        float r = p + bo[0];
        if (isf32) ((float*)out)[b] = r;
        else       ((__hip_bfloat16*)out)[b] = __float2bfloat16(r);
    }
}

extern "C" void kernel_launch(void* const* d_in, const int* in_sizes, int n_in,
                              void* d_out, int out_size, void* d_ws, size_t ws_size,
                              hipStream_t stream) {
    const int* aux  = (const int*)d_in[0];
    const int* uids = (const int*)d_in[1];
    const int* iids = (const int*)d_in[2];
    const int* grow = (const int*)d_in[3];
    const int* gcol = (const int*)d_in[4];

    char* p = (char*)d_ws;
    auto alloc = [&](size_t bytes) -> char* {
        char* r = p;
        p += (bytes + 255) / 256 * 256;
        return r;
    };
    // zero-region (one hipMemsetAsync): bucket_tot, cntf, moffs2
    int*   bucket_tot  = (int*)alloc(512 * 4);
    float* cntf        = (float*)alloc((size_t)3 * BATCH * 4);
    int2*  moffs2      = (int2*)alloc((size_t)180224 * 8);
    char*  zero_end    = p;
    float* Xpart       = (float*)alloc((size_t)NSLICE * BATCH * 64 * 4);  // fully written, no zeroing
    int*   bucket_base = (int*)alloc(512 * 4);
    int*   bucketcur   = (int*)alloc(512 * 4);
    int2*  moffs       = (int2*)alloc((size_t)180224 * 8);
    float* dinv        = (float*)alloc((size_t)180224 * 4);
    float* dsq         = (float*)alloc((size_t)180224 * 4);
    float* gsc         = (float*)alloc((size_t)180224 * 4);
    int*   binned      = (int*)alloc((size_t)E2 * 4);
    int*   cols        = (int*)alloc((size_t)E2 * 4);
    __half* embH       = (__half*)alloc((size_t)N_NODES * 64 * 2);
    __half* embA       = (__half*)alloc((size_t)N_NODES * 64 * 2);
    __half* embB       = (__half*)alloc((size_t)N_NODES * 64 * 2);
    float* tacc        = (float*)alloc((size_t)2048 * 64 * 4);
    unsigned short* WtG = (unsigned short*)alloc((size_t)KP_G * 64 * 2);
    unsigned short* WtD = (unsigned short*)alloc((size_t)KP_D * 64 * 2);
    unsigned short* WtA = (unsigned short*)alloc((size_t)KP_A * 64 * 2);
    float* ratef   = (float*)alloc(384 * 4);
    float* genderf = (float*)alloc(128 * 4);
    float* agef    = (float*)alloc(448 * 4);
    float* occf    = (float*)alloc(1344 * 4);
    float* areaf   = (float*)alloc((size_t)217728 * 4);
    float* fc1W    = (float*)alloc((size_t)40960 * 4);
    float* fc1b    = (float*)alloc(64 * 4);
    float* fc2W    = (float*)alloc(4096 * 4);
    float* fc2b    = (float*)alloc(64 * 4);
    float* outW    = (float*)alloc(64 * 4);
    float* outb    = (float*)alloc(4);

    const void* probe = d_in[14];   // user_rel, for inline dtype detect

    // 0. zero accumulators (single contiguous region, DMA)
    hipMemsetAsync(bucket_tot, 0, (size_t)(zero_end - (char*)bucket_tot), stream);

    // 1. fused prep: bucket counts (first) + table cvt + Wt pack
    CvtBatch cb;
    int blk = 0, si = 0;
    auto addseg = [&](const void* s, float* d, int n) {
        cb.seg[si].src = s; cb.seg[si].dst = d; cb.seg[si].n = n; cb.seg[si].blk0 = blk;
        blk += (n + 255) / 256; ++si;
    };
    addseg(d_in[6],  ratef,   384);
    addseg(d_in[10], genderf, 128);
    addseg(d_in[11], agef,    448);
    addseg(d_in[12], occf,    1344);
    addseg(d_in[13], areaf,   217728);
    addseg(d_in[16], fc1W,   40960);
    addseg(d_in[17], fc1b,   64);
    addseg(d_in[18], fc2W,   4096);
    addseg(d_in[19], fc2b,   64);
    addseg(d_in[20], outW,   64);
    addseg(d_in[21], outb,   1);
    for (int i = si; i < 16; ++i) { cb.seg[i].src = nullptr; cb.seg[i].dst = nullptr; cb.seg[i].n = 0; cb.seg[i].blk0 = 0x7fffffff; }
    const int cvtBlks = blk;
    hipLaunchKernelGGL(k_prep, dim3(BCNT_BLKS + cvtBlks + WT_BLKS), dim3(256), 0, stream,
                       cb, cvtBlks, d_in[7], d_in[8], d_in[9], WtG, WtD, WtA, grow, bucket_tot, probe);

    // 2. CSR build (p1 carries mhgemm + cvt + tacc0 as overlap cargo)
    hipLaunchKernelGGL(k_bscan, dim3(1), dim3(512), 0, stream, bucket_tot, bucket_base, bucketcur);
    hipLaunchKernelGGL(k_p1, dim3(MH_BLKS + BCNT_BLKS + CVT_BLKS + 512), dim3(256), 0, stream,
                       grow, gcol, bucketcur, binned, aux, WtG, WtD, WtA, Xpart, cntf,
                       d_in[14], d_in[15], embH, tacc, uids, iids);
    hipLaunchKernelGGL(k_p2, dim3(NBKT), dim3(256), 0, stream, binned, bucket_base, cols, moffs, dinv, dsq, gsc);

    // 3. LightGCN. L1 gathers embH (f16) with per-edge dinv + mark cargo;
    //    L2 in half domain + tacc-f1 cargo; L3 fused into mlp.
    const int spmvN = N_NODES / 32;           // 8 rows/wave * 4 waves/block
    hipLaunchKernelGGL(k_spmv_w, dim3(spmvN + 512), dim3(256), 0, stream,
                       embH, embB, moffs, cols, dinv, dsq, spmvN, uids, iids, moffs2);
    hipLaunchKernelGGL(k_spmv, dim3(spmvN + 512), dim3(256), 0, stream,
                       embB, embA, moffs2, cols, dsq, spmvN, tacc, uids, iids, gsc);

    // 4. fused spmv3 + X + MLP -> out
    hipLaunchKernelGGL(k_mlp, dim3(BATCH / 4), dim3(256), 0, stream,
                       aux, ratef, genderf, agef, occf, areaf, tacc, Xpart, cntf,
                       fc1W, fc1b, fc2W, fc2b, outW, outb, d_out, probe,
                       embA, moffs, cols, dinv, gsc, uids, iids);
}